// Round 1
// baseline (779.948 us; speedup 1.0000x reference)
//
#include <hip/hip_runtime.h>
#include <hip/hip_bf16.h>

#define NN 50000
#define NE 800000
#define DD 64
#define HH 128
#define KK 192   // 3*DD

typedef __bf16 bf16;
typedef __attribute__((ext_vector_type(8))) __bf16 bf16x8;
typedef __attribute__((ext_vector_type(4))) __bf16 bf16x4;
typedef __attribute__((ext_vector_type(4))) float f32x4;

// jax.nn.gelu(approximate=True): 0.5x(1+tanh(sqrt(2/pi)(x+0.044715x^3)))
//   = x * sigmoid(2*sqrt(2/pi)*(x+0.044715x^3))
__device__ __forceinline__ float gelu_tanh(float x) {
    float v = 1.5957691216057308f * x * (1.0f + 0.044715f * x * x);
    return x / (1.0f + __expf(-v));
}

// ---------------------------------------------------------------------------
// Edge kernel: tile of 64 edges per block iteration, 4 waves, 16 rows/wave.
// GEMM1: h[16x128] = X[16x192] @ W1 ; GELU ; GEMM2: y[16x64] = h @ W2 ; LN.
// MFMA 16x16x32 bf16 layouts (verified, learn_hip m89/m91/m120):
//   A[m][k]: m = lane&15, k = (lane>>4)*8 + j   (8 bf16 per lane)
//   B[k][n]: n = lane&15, k = (lane>>4)*8 + j
//   C/D:     col = lane&15, row = (lane>>4)*4 + reg
// ---------------------------------------------------------------------------
extern "C" __global__ void __launch_bounds__(256, 1)
edge_mlp_kernel(const float* __restrict__ ndata, const float* __restrict__ edata,
                const int* __restrict__ src, const int* __restrict__ dst,
                const float* __restrict__ W1, const float* __restrict__ b1,
                const float* __restrict__ W2, const float* __restrict__ b2,
                const float* __restrict__ gam, const float* __restrict__ bet,
                float* __restrict__ eout,
                float* __restrict__ eu, float* __restrict__ ev,
                float* __restrict__ cnts, float* __restrict__ cntd)
{
    __shared__ __align__(16) bf16 W1T[HH][200];     // [n][k], 51200 B
    __shared__ __align__(16) bf16 W2T[DD][136];     // [n][k], 17408 B
    __shared__ __align__(16) bf16 Xs[64][200];      // [row][k], 25600 B
    __shared__ __align__(16) bf16 Hs[4][16][136];   // per-wave h, 17408 B

    const int tid = threadIdx.x;
    // stage weights transposed to bf16 (once per block)
    for (int i = tid; i < KK * HH; i += 256) W1T[i % HH][i / HH] = (bf16)W1[i];
    for (int i = tid; i < HH * DD; i += 256) W2T[i % DD][i / DD] = (bf16)W2[i];
    __syncthreads();

    const int wave = tid >> 6;
    const int lane = tid & 63;
    const int l15  = lane & 15;
    const int quad = lane >> 4;
    const int r_st = tid >> 2;   // staging row 0..63 (wave-private: rows wave*16..+15)
    const int l_st = tid & 3;

    float b1v[8], b2v[4], gv[4], bv[4];
#pragma unroll
    for (int nt = 0; nt < 8; ++nt) b1v[nt] = b1[nt * 16 + l15];
#pragma unroll
    for (int nt = 0; nt < 4; ++nt) {
        b2v[nt] = b2[nt * 16 + l15];
        gv[nt]  = gam[nt * 16 + l15];
        bv[nt]  = bet[nt * 16 + l15];
    }

    for (int tile = blockIdx.x; tile < NE / 64; tile += gridDim.x) {
        const int e0 = tile * 64;
        // degree counts (one edge per thread, threads 0..63)
        if (tid < 64) {
            atomicAdd(&cnts[src[e0 + tid]], 1.0f);
            atomicAdd(&cntd[dst[e0 + tid]], 1.0f);
        }
        // gather X = [ndata[src] | ndata[dst] | edata] -> bf16 LDS
        {
            const int e = e0 + r_st;
            const float* base0 = ndata + (size_t)src[e] * DD;
            const float* base1 = ndata + (size_t)dst[e] * DD;
            const float* base2 = edata + (size_t)e * DD;
#pragma unroll
            for (int seg = 0; seg < 3; ++seg) {
                const float* bp = (seg == 0) ? base0 : ((seg == 1) ? base1 : base2);
#pragma unroll
                for (int jj = 0; jj < 4; ++jj) {
                    const int kk = l_st * 16 + jj * 4;
                    const float4 v = *(const float4*)(bp + kk);
                    bf16x4 w = { (bf16)v.x, (bf16)v.y, (bf16)v.z, (bf16)v.w };
                    *(bf16x4*)&Xs[r_st][seg * 64 + kk] = w;
                }
            }
        }
        // GEMM1
        const int arow = wave * 16 + l15;
        bf16x8 af[6];
#pragma unroll
        for (int s = 0; s < 6; ++s)
            af[s] = *(const bf16x8*)&Xs[arow][s * 32 + quad * 8];
#pragma unroll
        for (int nt = 0; nt < 8; ++nt) {
            f32x4 acc = {0.f, 0.f, 0.f, 0.f};
#pragma unroll
            for (int s = 0; s < 6; ++s) {
                bf16x8 bfr = *(const bf16x8*)&W1T[nt * 16 + l15][s * 32 + quad * 8];
                acc = __builtin_amdgcn_mfma_f32_16x16x32_bf16(af[s], bfr, acc, 0, 0, 0);
            }
#pragma unroll
            for (int r = 0; r < 4; ++r)
                Hs[wave][quad * 4 + r][nt * 16 + l15] = (bf16)gelu_tanh(acc[r] + b1v[nt]);
        }
        // GEMM2 (Hs is wave-private; DS ops in-order per wave, no barrier needed)
        bf16x8 af2[4];
#pragma unroll
        for (int s = 0; s < 4; ++s)
            af2[s] = *(const bf16x8*)&Hs[wave][l15][s * 32 + quad * 8];
        float yv[4][4];
        float ps[4] = {0.f, 0.f, 0.f, 0.f}, pq[4] = {0.f, 0.f, 0.f, 0.f};
#pragma unroll
        for (int nt = 0; nt < 4; ++nt) {
            f32x4 acc = {0.f, 0.f, 0.f, 0.f};
#pragma unroll
            for (int s = 0; s < 4; ++s) {
                bf16x8 bfr = *(const bf16x8*)&W2T[nt * 16 + l15][s * 32 + quad * 8];
                acc = __builtin_amdgcn_mfma_f32_16x16x32_bf16(af2[s], bfr, acc, 0, 0, 0);
            }
#pragma unroll
            for (int r = 0; r < 4; ++r) {
                const float y = acc[r] + b2v[nt];
                yv[nt][r] = y;
                ps[r] += y;
                pq[r] += y * y;
            }
        }
        // LayerNorm: row (quad*4+r) lives in this quad's 16 lanes, 4 cols each
#pragma unroll
        for (int m = 1; m < 16; m <<= 1) {
#pragma unroll
            for (int r = 0; r < 4; ++r) {
                ps[r] += __shfl_xor(ps[r], m, 64);
                pq[r] += __shfl_xor(pq[r], m, 64);
            }
        }
#pragma unroll
        for (int r = 0; r < 4; ++r) {
            const int row = e0 + wave * 16 + quad * 4 + r;
            const float mu  = ps[r] * (1.0f / 64.0f);
            const float var = pq[r] * (1.0f / 64.0f) - mu * mu;
            const float rs  = rsqrtf(var + 1e-5f);
            const int si = src[row], di = dst[row];
#pragma unroll
            for (int nt = 0; nt < 4; ++nt) {
                const int col = nt * 16 + l15;
                const float o = (yv[nt][r] - mu) * rs * gv[nt] + bv[nt];
                eout[(size_t)row * DD + col] = o;
                atomicAdd(&eu[(size_t)si * DD + col], o);
                atomicAdd(&ev[(size_t)di * DD + col], o);
            }
        }
    }
}

// ---------------------------------------------------------------------------
// Node kernel: one 64-row tile per block; x_n = [e_u | e_v | ndata]
// ---------------------------------------------------------------------------
extern "C" __global__ void __launch_bounds__(256, 1)
node_mlp_kernel(const float* __restrict__ ndata,
                const float* __restrict__ eu, const float* __restrict__ ev,
                const float* __restrict__ cnts, const float* __restrict__ cntd,
                const float* __restrict__ W1, const float* __restrict__ b1,
                const float* __restrict__ W2, const float* __restrict__ b2,
                const float* __restrict__ gam, const float* __restrict__ bet,
                float* __restrict__ nout)
{
    __shared__ __align__(16) bf16 W1T[HH][200];
    __shared__ __align__(16) bf16 W2T[DD][136];
    __shared__ __align__(16) bf16 Xs[64][200];
    __shared__ __align__(16) bf16 Hs[4][16][136];

    const int tid = threadIdx.x;
    for (int i = tid; i < KK * HH; i += 256) W1T[i % HH][i / HH] = (bf16)W1[i];
    for (int i = tid; i < HH * DD; i += 256) W2T[i % DD][i / DD] = (bf16)W2[i];
    __syncthreads();

    const int wave = tid >> 6;
    const int lane = tid & 63;
    const int l15  = lane & 15;
    const int quad = lane >> 4;
    const int r_st = tid >> 2;
    const int l_st = tid & 3;

    float b1v[8], b2v[4], gv[4], bv[4];
#pragma unroll
    for (int nt = 0; nt < 8; ++nt) b1v[nt] = b1[nt * 16 + l15];
#pragma unroll
    for (int nt = 0; nt < 4; ++nt) {
        b2v[nt] = b2[nt * 16 + l15];
        gv[nt]  = gam[nt * 16 + l15];
        bv[nt]  = bet[nt * 16 + l15];
    }

    const int n0 = blockIdx.x * 64;
    // gather x_n = [eu/cnt_s | ev/cnt_d | ndata] -> bf16 LDS (segment-mean fused)
    {
        const int n = n0 + r_st;
        if (n < NN) {
            const float is  = 1.0f / fmaxf(cnts[n], 1.0f);
            const float idv = 1.0f / fmaxf(cntd[n], 1.0f);
            const float* base0 = eu + (size_t)n * DD;
            const float* base1 = ev + (size_t)n * DD;
            const float* base2 = ndata + (size_t)n * DD;
#pragma unroll
            for (int seg = 0; seg < 3; ++seg) {
                const float* bp = (seg == 0) ? base0 : ((seg == 1) ? base1 : base2);
                const float sc = (seg == 0) ? is : ((seg == 1) ? idv : 1.0f);
#pragma unroll
                for (int jj = 0; jj < 4; ++jj) {
                    const int kk = l_st * 16 + jj * 4;
                    const float4 v = *(const float4*)(bp + kk);
                    bf16x4 w = { (bf16)(v.x * sc), (bf16)(v.y * sc),
                                 (bf16)(v.z * sc), (bf16)(v.w * sc) };
                    *(bf16x4*)&Xs[r_st][seg * 64 + kk] = w;
                }
            }
        } else {
            bf16x4 z = { (bf16)0.f, (bf16)0.f, (bf16)0.f, (bf16)0.f };
#pragma unroll
            for (int seg = 0; seg < 3; ++seg)
#pragma unroll
                for (int jj = 0; jj < 4; ++jj)
                    *(bf16x4*)&Xs[r_st][seg * 64 + l_st * 16 + jj * 4] = z;
        }
    }
    // GEMM1
    const int arow = wave * 16 + l15;
    bf16x8 af[6];
#pragma unroll
    for (int s = 0; s < 6; ++s)
        af[s] = *(const bf16x8*)&Xs[arow][s * 32 + quad * 8];
#pragma unroll
    for (int nt = 0; nt < 8; ++nt) {
        f32x4 acc = {0.f, 0.f, 0.f, 0.f};
#pragma unroll
        for (int s = 0; s < 6; ++s) {
            bf16x8 bfr = *(const bf16x8*)&W1T[nt * 16 + l15][s * 32 + quad * 8];
            acc = __builtin_amdgcn_mfma_f32_16x16x32_bf16(af[s], bfr, acc, 0, 0, 0);
        }
#pragma unroll
        for (int r = 0; r < 4; ++r)
            Hs[wave][quad * 4 + r][nt * 16 + l15] = (bf16)gelu_tanh(acc[r] + b1v[nt]);
    }
    // GEMM2
    bf16x8 af2[4];
#pragma unroll
    for (int s = 0; s < 4; ++s)
        af2[s] = *(const bf16x8*)&Hs[wave][l15][s * 32 + quad * 8];
    float yv[4][4];
    float ps[4] = {0.f, 0.f, 0.f, 0.f}, pq[4] = {0.f, 0.f, 0.f, 0.f};
#pragma unroll
    for (int nt = 0; nt < 4; ++nt) {
        f32x4 acc = {0.f, 0.f, 0.f, 0.f};
#pragma unroll
        for (int s = 0; s < 4; ++s) {
            bf16x8 bfr = *(const bf16x8*)&W2T[nt * 16 + l15][s * 32 + quad * 8];
            acc = __builtin_amdgcn_mfma_f32_16x16x32_bf16(af2[s], bfr, acc, 0, 0, 0);
        }
#pragma unroll
        for (int r = 0; r < 4; ++r) {
            const float y = acc[r] + b2v[nt];
            yv[nt][r] = y;
            ps[r] += y;
            pq[r] += y * y;
        }
    }
#pragma unroll
    for (int m = 1; m < 16; m <<= 1) {
#pragma unroll
        for (int r = 0; r < 4; ++r) {
            ps[r] += __shfl_xor(ps[r], m, 64);
            pq[r] += __shfl_xor(pq[r], m, 64);
        }
    }
#pragma unroll
    for (int r = 0; r < 4; ++r) {
        const int row = n0 + wave * 16 + quad * 4 + r;
        if (row < NN) {
            const float mu  = ps[r] * (1.0f / 64.0f);
            const float var = pq[r] * (1.0f / 64.0f) - mu * mu;
            const float rs  = rsqrtf(var + 1e-5f);
#pragma unroll
            for (int nt = 0; nt < 4; ++nt) {
                const int col = nt * 16 + l15;
                nout[(size_t)row * DD + col] = (yv[nt][r] - mu) * rs * gv[nt] + bv[nt];
            }
        }
    }
}

extern "C" void kernel_launch(void* const* d_in, const int* in_sizes, int n_in,
                              void* d_out, int out_size, void* d_ws, size_t ws_size,
                              hipStream_t stream)
{
    const float* ndata = (const float*)d_in[0];
    const float* edata = (const float*)d_in[1];
    const int*   src   = (const int*)d_in[2];
    const int*   dst   = (const int*)d_in[3];
    const float* eW1 = (const float*)d_in[4];
    const float* eb1 = (const float*)d_in[5];
    const float* eW2 = (const float*)d_in[6];
    const float* eb2 = (const float*)d_in[7];
    const float* eg  = (const float*)d_in[8];
    const float* ebt = (const float*)d_in[9];
    const float* nW1 = (const float*)d_in[10];
    const float* nb1 = (const float*)d_in[11];
    const float* nW2 = (const float*)d_in[12];
    const float* nb2 = (const float*)d_in[13];
    const float* ng  = (const float*)d_in[14];
    const float* nbt = (const float*)d_in[15];

    float* out  = (float*)d_out;
    float* nout = out;                       // ndata_new [NN*DD]
    float* eout = out + (size_t)NN * DD;     // edata_new [NE*DD]

    float* eu   = (float*)d_ws;              // [NN*DD] scatter sum (src)
    float* ev   = eu + (size_t)NN * DD;      // [NN*DD] scatter sum (dst)
    float* cnts = ev + (size_t)NN * DD;      // [NN] degree (src)
    float* cntd = cnts + NN;                 // [NN] degree (dst)

    const size_t zbytes = ((size_t)2 * NN * DD + 2 * NN) * sizeof(float);
    hipMemsetAsync(d_ws, 0, zbytes, stream);

    hipLaunchKernelGGL(edge_mlp_kernel, dim3(1024), dim3(256), 0, stream,
                       ndata, edata, src, dst, eW1, eb1, eW2, eb2, eg, ebt,
                       eout, eu, ev, cnts, cntd);
    hipLaunchKernelGGL(node_mlp_kernel, dim3((NN + 63) / 64), dim3(256), 0, stream,
                       ndata, eu, ev, cnts, cntd, nW1, nb1, nW2, nb2, ng, nbt,
                       nout);
}